// Round 14
// baseline (264.433 us; speedup 1.0000x reference)
//
#include <hip/hip_runtime.h>

#define NPT   4096
#define KNN_K 16
#define EPSV  1e-5f

// ---- ws float layout ----
#define W1T_OFF 4352               // [64][64]  (ic-major)
#define B1_OFF  8448               // [64]
#define W2T_OFF 8512               // [64][128] (ic-major)
#define B2_OFF  16704              // [128]
#define IDX_OFF 16832              // int[4*4096*16]
#define P_OFF   344512             // float[16384][64]  P = W0p*pts + W0x*xyz + b0
#define Q_OFF   1393088            // float[16384][64]  Q = W0x*xyz

typedef unsigned long long ull;

__device__ __forceinline__ ull minu64(ull a, ull b) { return a < b ? a : b; }
__device__ __forceinline__ ull maxu64(ull a, ull b) { return a > b ? a : b; }

__device__ __forceinline__ ull bitonic_sort64(ull v, int lane) {
#pragma unroll
  for (int k = 2; k <= 64; k <<= 1) {
#pragma unroll
    for (int j = k >> 1; j > 0; j >>= 1) {
      ull o = __shfl_xor(v, j);
      bool lower = (lane & j) == 0;
      bool up = (lane & k) == 0;
      v = (lower == up) ? minu64(v, o) : maxu64(v, o);
    }
  }
  return v;
}

__device__ __forceinline__ ull bitonic_merge64(ull v, int lane) {
#pragma unroll
  for (int j = 32; j > 0; j >>= 1) {
    ull o = __shfl_xor(v, j);
    v = ((lane & j) == 0) ? minu64(v, o) : maxu64(v, o);
  }
  return v;
}

// One filter/flush step for one query against one lane-resident candidate.
// All state (thresh_hi, cnt) is wave-uniform; branches are wave-uniform.
__device__ __forceinline__ void filter_step(float4 q, float4 c, unsigned idx32,
                                            unsigned& thresh_hi, int& cnt,
                                            ull& R, ull* buf, int lane) {
  float dot = __fadd_rn(__fadd_rn(__fmul_rn(q.x, c.x), __fmul_rn(q.y, c.y)),
                        __fmul_rn(q.z, c.z));
  float d2 = __fsub_rn(__fadd_rn(q.w, c.w), __fmul_rn(2.0f, dot));
  unsigned bits = __float_as_uint(d2);
  unsigned fk = bits ^ (0x80000000u | (unsigned)((int)bits >> 31));
  bool pred = fk <= thresh_hi;     // superset of exact u64 test; flush is exact
  ull mask = __ballot(pred);
  if (mask) {
    int pos = cnt + (int)__builtin_amdgcn_mbcnt_hi(
                        (unsigned)(mask >> 32),
                        __builtin_amdgcn_mbcnt_lo((unsigned)mask, 0u));
    if (pred) buf[pos] = ((ull)fk << 32) | idx32;
    cnt += __popcll(mask);
    if (cnt >= 64) {
      ull v = buf[lane];
      v = bitonic_sort64(v, lane);
      ull vr = __shfl(v, 63 - lane);
      R = minu64(R, vr);
      R = bitonic_merge64(R, lane);
      thresh_hi = (unsigned)__shfl((int)(unsigned)(R >> 32), 15);
      cnt -= 64;
      if (lane < cnt) {
        ull tmp = buf[64 + lane];
        buf[lane] = tmp;
      }
    }
  }
}

__device__ __forceinline__ ull final_flush(ull R, int cnt, ull* buf, int lane) {
  ull v = (lane < cnt) ? buf[lane] : ~0ull;
  v = bitonic_sort64(v, lane);
  ull vr = __shfl(v, 63 - lane);
  R = minu64(R, vr);
  return bitonic_merge64(R, lane);
}

// MEGA kernel v16: knn SPLIT-CANDIDATE — a wave PAIR shares each query pair;
// wave half h scans candidates [2048h, 2048h+2048), then the two sorted
// top-64 lists merge via one LDS exchange + bitonic merge (the flush idiom).
// Halves the per-wave serial filter chain (R12: longer chain regressed ->
// knn is dependency-latency-bound) at constant total work, doubling TLP.
// Selection exact: each global top-16 key is inside its half's top-64;
// merge by full u64 key order; keys unique (idx in low bits).
//   blocks [0,4096):    KNN, 4 queries/block (dispatched FIRST, long pole)
//   blocks [4096,6144): P/Q, 2 points/wave (backfills knn's ragged tail)
//   blocks [6144,6193): W1/W2/bias fold for mlp
__global__ __launch_bounds__(256) void mega_kernel(
    const float* __restrict__ xyz, const float* __restrict__ points,
    const float* __restrict__ w0, const float* __restrict__ b0, const float* __restrict__ g0,
    const float* __restrict__ be0, const float* __restrict__ rm0, const float* __restrict__ rv0,
    const float* __restrict__ w1, const float* __restrict__ b1, const float* __restrict__ g1,
    const float* __restrict__ be1, const float* __restrict__ rm1, const float* __restrict__ rv1,
    const float* __restrict__ w2, const float* __restrict__ b2, const float* __restrict__ g2,
    const float* __restrict__ be2, const float* __restrict__ rm2, const float* __restrict__ rv2,
    float* __restrict__ ws, int* __restrict__ knnOut) {
  __shared__ __align__(16) unsigned char smem[20480];  // knn: 8K flush bufs; pq: 17.2K w0
  int blk = blockIdx.x;
  int tid = threadIdx.x;

  if (blk < 4096) {
    // ------ KNN: wave pair = 2 queries; each wave scans half the candidates
    ull* bufb = (ull*)smem;                       // [4 waves][256] ull
    int lane = tid & 63, w = tid >> 6;
    int pairId = w >> 1, half = w & 1;
    int b = blk >> 10;                            // 1024 blocks per batch
    int n0 = ((blk & 1023) << 2) + (pairId << 1);
    int n1 = n0 + 1;
    const float* xb = xyz + (size_t)b * NPT * 3;
    ull* buf0 = bufb + w * 256;
    ull* buf1 = buf0 + 128;

    float4 q0, q1;
    {
      const float* qp = xb + n0 * 3;
      float ax = qp[0], ay = qp[1], az = qp[2];
      float bx = qp[3], by = qp[4], bz = qp[5];
      q0 = make_float4(ax, ay, az,
          __fadd_rn(__fadd_rn(__fmul_rn(ax, ax), __fmul_rn(ay, ay)), __fmul_rn(az, az)));
      q1 = make_float4(bx, by, bz,
          __fadd_rn(__fadd_rn(__fmul_rn(bx, bx), __fmul_rn(by, by)), __fmul_rn(bz, bz)));
    }
    ull R0 = ~0ull, R1 = ~0ull;
    unsigned th0 = 0xFFFFFFFFu, th1 = 0xFFFFFFFFu;
    int cnt0 = 0, cnt1 = 0;

    int gstart = half << 11;                      // 2048 candidates per half
    // iter-0 preload (lane-resident candidate)
    float cx = xb[3 * (gstart + lane)], cy = xb[3 * (gstart + lane) + 1],
          cz = xb[3 * (gstart + lane) + 2];
#pragma unroll 1
    for (int g = gstart; g < gstart + 2048; g += 64) {
      // prefetch next group (wrapped within half on last iter; values unused)
      int ni = 3 * (gstart + ((g + 64 - gstart + lane) & 2047));
      float nx = xb[ni], ny = xb[ni + 1], nz = xb[ni + 2];
      float csq = __fadd_rn(__fadd_rn(__fmul_rn(cx, cx), __fmul_rn(cy, cy)),
                            __fmul_rn(cz, cz));
      float4 c = make_float4(cx, cy, cz, csq);
      unsigned idx32 = (unsigned)(g + lane);
      filter_step(q0, c, idx32, th0, cnt0, R0, buf0, lane);
      filter_step(q1, c, idx32, th1, cnt1, R1, buf1, lane);
      cx = nx; cy = ny; cz = nz;
    }
    R0 = final_flush(R0, cnt0, buf0, lane);
    R1 = final_flush(R1, cnt1, buf1, lane);

    // ---- cross-wave merge: exchange sorted top-64 lists via LDS ----
    buf0[lane] = R0;                              // flush bufs are free now
    buf0[64 + lane] = R1;
    __syncthreads();
    {
      ull* pbuf = bufb + (w ^ 1) * 256;           // partner wave's lists
      ull o0 = pbuf[63 - lane];
      ull o1 = pbuf[64 + (63 - lane)];
      R0 = bitonic_merge64(minu64(R0, o0), lane);
      R1 = bitonic_merge64(minu64(R1, o1), lane);
    }
    if (half == 0 && lane < KNN_K) {
      knnOut[(b * NPT + n0) * KNN_K + lane] = (int)(unsigned)(R0 & 0xFFFFFFFFull);
      knnOut[(b * NPT + n1) * KNN_K + lane] = (int)(unsigned)(R1 & 0xFFFFFFFFull);
    }
    return;
  }

  if (blk < 6144) {
    // ---------------- P/Q precompute: 2 points per wave ------------------
    float* wlds = (float*)smem;                   // [64*67] folded w0
    for (int j = tid; j < 4288; j += 256) {
      int r = j / 67;
      float s = g0[r] * rsqrtf(rv0[r] + EPSV);
      wlds[j] = __fmul_rn(w0[j], s);
    }
    __syncthreads();
    int oc = tid & 63;
    int base = (blk - 4096) * 8 + (tid >> 6);
    float s = g0[oc] * rsqrtf(rv0[oc] + EPSV);
    float b0f = (b0[oc] - rm0[oc]) * s + be0[oc];
    const float* wrow = wlds + oc * 67;           // stride-67 -> 2-way bank (free)
#pragma unroll 1
    for (int pt = 0; pt < 2; ++pt) {
      int i = base + pt * 4;
      float x = xyz[i * 3], y = xyz[i * 3 + 1], z = xyz[i * 3 + 2];
      float qacc = wrow[0] * x;
      qacc = fmaf(wrow[1], y, qacc);
      qacc = fmaf(wrow[2], z, qacc);
      float acc = b0f + qacc;
      const float* prow = points + (size_t)i * 64;
#pragma unroll 4
      for (int c = 0; c < 64; ++c) acc = fmaf(wrow[3 + c], prow[c], acc);
      ws[P_OFF + (size_t)i * 64 + oc] = acc;
      ws[Q_OFF + (size_t)i * 64 + oc] = qacc;
    }
    return;
  }

  // ---------------- weight fold for mlp (W1T/B1/W2T/B2) ------------------
  {
    int i = (blk - 6144) * 256 + tid + 4352;
    if (i < 8448) {
      int j = i - 4352; int oc = j & 63, ic = j >> 6;
      float s = g1[oc] * rsqrtf(rv1[oc] + EPSV);
      ws[i] = w1[oc * 64 + ic] * s;
    } else if (i < 8512) {
      int oc = i - 8448;
      float s = g1[oc] * rsqrtf(rv1[oc] + EPSV);
      ws[i] = (b1[oc] - rm1[oc]) * s + be1[oc];
    } else if (i < 16704) {
      int j = i - 8512; int ic = j >> 7, oc = j & 127;
      float s = g2[oc] * rsqrtf(rv2[oc] + EPSV);
      ws[i] = w2[oc * 64 + ic] * s;               // w2t [ic][oc]
    } else if (i < 16832) {
      int oc = i - 16704;
      float s = g2[oc] * rsqrtf(rv2[oc] + EPSV);
      ws[i] = (b2[oc] - rm2[oc]) * s + be2[oc];
    }
  }
}

// MLP v14 kept byte-identical (best measured; dist-2 pipelined GEMM, 40 KB
// LDS, 4 blocks/CU). Accumulation order bias + ic 0..63 -> bit-identical.
__global__ __launch_bounds__(256, 4) void mlp_kernel(
    const float* __restrict__ wbuf, const int* __restrict__ knn,
    float* __restrict__ out) {
  __shared__ __align__(16) float Ash[64 * 128];   // 32 KB [ic][p]
  __shared__ __align__(16) float Wsh[32 * 64];    // 8 KB chunk [icLocal][oc]
  int tid = threadIdx.x;
  int qblk = blockIdx.x << 3;                     // 8 flat queries per block

  const float4* w1g = (const float4*)(wbuf + W1T_OFF);   // [64][16 f4]
  const float4* w2g = (const float4*)(wbuf + W2T_OFF);   // [64][32 f4]
  float4* wl = (float4*)Wsh;

  // W2 chunk (pass p, ic-half h) entry e in [0,512): row 32h+(e>>4), colf4 16p+(e&15)
#define W2IDX(e, p, h) ((((h) << 5) + ((e) >> 4)) * 32 + ((p) << 4) + ((e) & 15))

  // ---- preload W1a ----
  float4 s0 = w1g[tid];
  float4 s1 = w1g[256 + tid];

  // ---- h0: pair p = tid&127, ic-half = tid>>7 ----
  {
    int p = tid & 127, half = tid >> 7;
    int q = qblk + (p >> 4);
    int k = p & 15;
    int src = knn[q * KNN_K + k];                 // coalesced across 128 threads
    int srow = (q & ~(NPT - 1)) + src;
    const float4* Pp = (const float4*)(wbuf + P_OFF + (size_t)srow * 64 + half * 32);
    const float4* Qp = (const float4*)(wbuf + Q_OFF + (size_t)q * 64 + half * 32);
#pragma unroll
    for (int j = 0; j < 8; ++j) {
      float4 pv = Pp[j];
      float4 qv = Qp[j];
      int ic = half * 32 + j * 4;
      Ash[(ic + 0) * 128 + p] = fmaxf(pv.x - qv.x, 0.0f);
      Ash[(ic + 1) * 128 + p] = fmaxf(pv.y - qv.y, 0.0f);
      Ash[(ic + 2) * 128 + p] = fmaxf(pv.z - qv.z, 0.0f);
      Ash[(ic + 3) * 128 + p] = fmaxf(pv.w - qv.w, 0.0f);
    }
  }
  // write W1a; preload W1b
  wl[tid] = s0; wl[256 + tid] = s1;
  s0 = w1g[512 + tid]; s1 = w1g[768 + tid];
  __syncthreads();                                 // S1: h0 + W1a visible

  int og = tid & 7, pg = tid >> 3;                 // 32 pgrp x 8 ogrp
  const float* Arow = Ash + 4 * pg;
  const float* Wrow = Wsh + 8 * og;
  float acc[4][8];                                 // [pair][oc]

  // distance-2 software-pipelined 32-ic GEMM: loads for ic+2 issue before
  // the FMAs of ic; all register names static after full unroll.
#define LD_A(R0, i)  (*(const float4*)(Arow + ((R0) + (i)) * 128))
#define LD_W0(i)     (*(const float4*)(Wrow + (i) * 64))
#define LD_W1(i)     (*(const float4*)(Wrow + (i) * 64 + 4))
#define GEMM32(R0)                                                        \
  {                                                                       \
    float4 aA = LD_A(R0, 0), wA0 = LD_W0(0), wA1 = LD_W1(0);              \
    float4 aB = LD_A(R0, 1), wB0 = LD_W0(1), wB1 = LD_W1(1);              \
    _Pragma("unroll")                                                     \
    for (int ic = 0; ic < 32; ++ic) {                                     \
      int nx = (ic + 2 <= 31) ? ic + 2 : 31;                              \
      float4 aN = LD_A(R0, nx);                                           \
      float4 wN0 = LD_W0(nx);                                             \
      float4 wN1 = LD_W1(nx);                                             \
      float av[4] = {aA.x, aA.y, aA.z, aA.w};                             \
      float wv[8] = {wA0.x, wA0.y, wA0.z, wA0.w, wA1.x, wA1.y, wA1.z, wA1.w};\
      _Pragma("unroll")                                                   \
      for (int ii = 0; ii < 4; ++ii)                                      \
        _Pragma("unroll")                                                 \
        for (int jj = 0; jj < 8; ++jj) acc[ii][jj] = fmaf(av[ii], wv[jj], acc[ii][jj]); \
      aA = aB; wA0 = wB0; wA1 = wB1;                                      \
      aB = aN; wB0 = wN0; wB1 = wN1;                                      \
    }                                                                     \
  }

  // ---- layer 1 ----
  {
    float4 b0v = *(const float4*)(wbuf + B1_OFF + 8 * og);
    float4 b1v = *(const float4*)(wbuf + B1_OFF + 8 * og + 4);
    float bj[8] = {b0v.x, b0v.y, b0v.z, b0v.w, b1v.x, b1v.y, b1v.z, b1v.w};
#pragma unroll
    for (int i = 0; i < 4; ++i)
#pragma unroll
      for (int j = 0; j < 8; ++j) acc[i][j] = bj[j];
  }
  GEMM32(0)                                        // W1a: ic 0..31
  __syncthreads();                                 // S2: W1a reads done
  wl[tid] = s0; wl[256 + tid] = s1;                // write W1b
  s0 = w2g[W2IDX(tid, 0, 0)]; s1 = w2g[W2IDX(tid + 256, 0, 0)];
  __syncthreads();                                 // S3: W1b visible
  GEMM32(32)                                       // W1b: ic 32..63
  __syncthreads();                                 // S4: all Ash(h0)+W1b reads done

  // h1 -> A[oc][p] (write throughput-limited, once per layer: accepted)
#pragma unroll
  for (int j = 0; j < 8; ++j) {
    int oc = 8 * og + j;
    *(float4*)(Ash + oc * 128 + 4 * pg) =
        make_float4(fmaxf(acc[0][j], 0.0f), fmaxf(acc[1][j], 0.0f),
                    fmaxf(acc[2][j], 0.0f), fmaxf(acc[3][j], 0.0f));
  }
  // stage W2p0a from regs; preload W2p0b
  wl[tid] = s0; wl[256 + tid] = s1;
  s0 = w2g[W2IDX(tid, 0, 1)]; s1 = w2g[W2IDX(tid + 256, 0, 1)];
  __syncthreads();                                 // S5: h1 + W2p0a visible

  int qout = qblk + (pg >> 2);
  float* obase = out + (size_t)qout * 128 + 8 * og;

  // ---- layer 2 pass 0 (oc 0..63) ----
  {
    float4 b0v = *(const float4*)(wbuf + B2_OFF + 8 * og);
    float4 b1v = *(const float4*)(wbuf + B2_OFF + 8 * og + 4);
    float bj[8] = {b0v.x, b0v.y, b0v.z, b0v.w, b1v.x, b1v.y, b1v.z, b1v.w};
#pragma unroll
    for (int i = 0; i < 4; ++i)
#pragma unroll
      for (int j = 0; j < 8; ++j) acc[i][j] = bj[j];
  }
  GEMM32(0)                                        // W2p0a: ic 0..31
  __syncthreads();                                 // S6
  wl[tid] = s0; wl[256 + tid] = s1;                // write W2p0b
  s0 = w2g[W2IDX(tid, 1, 0)]; s1 = w2g[W2IDX(tid + 256, 1, 0)];
  __syncthreads();                                 // S7
  GEMM32(32)                                       // W2p0b: ic 32..63
  {
    float m[8];
#pragma unroll
    for (int j = 0; j < 8; ++j) {
      float v = fmaxf(fmaxf(acc[0][j], acc[1][j]), fmaxf(acc[2][j], acc[3][j]));
      v = fmaxf(v, 0.0f);
      v = fmaxf(v, __shfl_xor(v, 8));              // pg bit 0
      m[j] = fmaxf(v, __shfl_xor(v, 16));          // pg bit 1
    }
    if ((pg & 3) == 0) {
      *(float4*)(obase)     = make_float4(m[0], m[1], m[2], m[3]);
      *(float4*)(obase + 4) = make_float4(m[4], m[5], m[6], m[7]);
    }
  }
  __syncthreads();                                 // S8
  wl[tid] = s0; wl[256 + tid] = s1;                // write W2p1a
  s0 = w2g[W2IDX(tid, 1, 1)]; s1 = w2g[W2IDX(tid + 256, 1, 1)];
  __syncthreads();                                 // S9

  // ---- layer 2 pass 1 (oc 64..127) ----
  {
    float4 b0v = *(const float4*)(wbuf + B2_OFF + 64 + 8 * og);
    float4 b1v = *(const float4*)(wbuf + B2_OFF + 64 + 8 * og + 4);
    float bj[8] = {b0v.x, b0v.y, b0v.z, b0v.w, b1v.x, b1v.y, b1v.z, b1v.w};
#pragma unroll
    for (int i = 0; i < 4; ++i)
#pragma unroll
      for (int j = 0; j < 8; ++j) acc[i][j] = bj[j];
  }
  GEMM32(0)                                        // W2p1a: ic 0..31
  __syncthreads();                                 // S10
  wl[tid] = s0; wl[256 + tid] = s1;                // write W2p1b
  __syncthreads();                                 // S11
  GEMM32(32)                                       // W2p1b: ic 32..63
  {
    float m[8];
#pragma unroll
    for (int j = 0; j < 8; ++j) {
      float v = fmaxf(fmaxf(acc[0][j], acc[1][j]), fmaxf(acc[2][j], acc[3][j]));
      v = fmaxf(v, 0.0f);
      v = fmaxf(v, __shfl_xor(v, 8));
      m[j] = fmaxf(v, __shfl_xor(v, 16));
    }
    if ((pg & 3) == 0) {
      *(float4*)(obase + 64)     = make_float4(m[0], m[1], m[2], m[3]);
      *(float4*)(obase + 64 + 4) = make_float4(m[4], m[5], m[6], m[7]);
    }
  }
#undef GEMM32
#undef LD_A
#undef LD_W0
#undef LD_W1
#undef W2IDX
}

extern "C" void kernel_launch(void* const* d_in, const int* in_sizes, int n_in,
                              void* d_out, int out_size, void* d_ws, size_t ws_size,
                              hipStream_t stream) {
  const float* xyz    = (const float*)d_in[0];
  const float* points = (const float*)d_in[1];
  float* wsF = (float*)d_ws;
  int* idxBuf = (int*)(wsF + IDX_OFF);

  mega_kernel<<<6193, 256, 0, stream>>>(
      xyz, points,
      (const float*)d_in[2],  (const float*)d_in[3],  (const float*)d_in[4],
      (const float*)d_in[5],  (const float*)d_in[6],  (const float*)d_in[7],
      (const float*)d_in[8],  (const float*)d_in[9],  (const float*)d_in[10],
      (const float*)d_in[11], (const float*)d_in[12], (const float*)d_in[13],
      (const float*)d_in[14], (const float*)d_in[15], (const float*)d_in[16],
      (const float*)d_in[17], (const float*)d_in[18], (const float*)d_in[19],
      wsF, idxBuf);
  mlp_kernel<<<2048, 256, 0, stream>>>(wsF, idxBuf, (float*)d_out);
}

// Round 15
// 238.598 us; speedup vs baseline: 1.1083x; 1.1083x over previous
//
#include <hip/hip_runtime.h>

#define NPT   4096
#define KNN_K 16
#define EPSV  1e-5f

// ---- ws float layout ----
#define W1T_OFF 4352               // [64][64]  (ic-major)
#define B1_OFF  8448               // [64]
#define W2T_OFF 8512               // [64][128] (ic-major)
#define B2_OFF  16704              // [128]
#define IDX_OFF 16832              // int[4*4096*16]
#define P_OFF   344512             // float[16384][64]  P = W0p*pts + W0x*xyz + b0
#define Q_OFF   1393088            // float[16384][64]  Q = W0x*xyz

typedef unsigned long long ull;

__device__ __forceinline__ ull minu64(ull a, ull b) { return a < b ? a : b; }
__device__ __forceinline__ ull maxu64(ull a, ull b) { return a > b ? a : b; }

__device__ __forceinline__ ull bitonic_sort64(ull v, int lane) {
#pragma unroll
  for (int k = 2; k <= 64; k <<= 1) {
#pragma unroll
    for (int j = k >> 1; j > 0; j >>= 1) {
      ull o = __shfl_xor(v, j);
      bool lower = (lane & j) == 0;
      bool up = (lane & k) == 0;
      v = (lower == up) ? minu64(v, o) : maxu64(v, o);
    }
  }
  return v;
}

__device__ __forceinline__ ull bitonic_merge64(ull v, int lane) {
#pragma unroll
  for (int j = 32; j > 0; j >>= 1) {
    ull o = __shfl_xor(v, j);
    v = ((lane & j) == 0) ? minu64(v, o) : maxu64(v, o);
  }
  return v;
}

// One filter/flush step for one query against one lane-resident candidate.
// All state (thresh_hi, cnt) is wave-uniform; branches are wave-uniform.
__device__ __forceinline__ void filter_step(float4 q, float4 c, unsigned idx32,
                                            unsigned& thresh_hi, int& cnt,
                                            ull& R, ull* buf, int lane) {
  float dot = __fadd_rn(__fadd_rn(__fmul_rn(q.x, c.x), __fmul_rn(q.y, c.y)),
                        __fmul_rn(q.z, c.z));
  float d2 = __fsub_rn(__fadd_rn(q.w, c.w), __fmul_rn(2.0f, dot));
  unsigned bits = __float_as_uint(d2);
  unsigned fk = bits ^ (0x80000000u | (unsigned)((int)bits >> 31));
  bool pred = fk <= thresh_hi;     // superset of exact u64 test; flush is exact
  ull mask = __ballot(pred);
  if (mask) {
    int pos = cnt + (int)__builtin_amdgcn_mbcnt_hi(
                        (unsigned)(mask >> 32),
                        __builtin_amdgcn_mbcnt_lo((unsigned)mask, 0u));
    if (pred) buf[pos] = ((ull)fk << 32) | idx32;
    cnt += __popcll(mask);
    if (cnt >= 64) {
      ull v = buf[lane];
      v = bitonic_sort64(v, lane);
      ull vr = __shfl(v, 63 - lane);
      R = minu64(R, vr);
      R = bitonic_merge64(R, lane);
      thresh_hi = (unsigned)__shfl((int)(unsigned)(R >> 32), 15);
      cnt -= 64;
      if (lane < cnt) {
        ull tmp = buf[64 + lane];
        buf[lane] = tmp;
      }
    }
  }
}

__device__ __forceinline__ ull final_flush(ull R, int cnt, ull* buf, int lane) {
  ull v = (lane < cnt) ? buf[lane] : ~0ull;
  v = bitonic_sort64(v, lane);
  ull vr = __shfl(v, 63 - lane);
  R = minu64(R, vr);
  return bitonic_merge64(R, lane);
}

// MEGA kernel v12 restored byte-identical (mega ~76us; best measured knn).
// R14's split-candidate variant regressed to ~121us: half-local thresholds
// converge to top-64 not top-16 -> ~2x flush work. Exploration closed:
// 2q/wave register-direct is the verified knn local optimum.
//   blocks [0,2048):    KNN, 8 queries/block (dispatched FIRST, long pole)
//   blocks [2048,4096): P/Q, 2 points/wave (backfills knn's ragged tail)
//   blocks [4096,4145): W1/W2/bias fold for mlp
__global__ __launch_bounds__(256) void mega_kernel(
    const float* __restrict__ xyz, const float* __restrict__ points,
    const float* __restrict__ w0, const float* __restrict__ b0, const float* __restrict__ g0,
    const float* __restrict__ be0, const float* __restrict__ rm0, const float* __restrict__ rv0,
    const float* __restrict__ w1, const float* __restrict__ b1, const float* __restrict__ g1,
    const float* __restrict__ be1, const float* __restrict__ rm1, const float* __restrict__ rv1,
    const float* __restrict__ w2, const float* __restrict__ b2, const float* __restrict__ g2,
    const float* __restrict__ be2, const float* __restrict__ rm2, const float* __restrict__ rv2,
    float* __restrict__ ws, int* __restrict__ knnOut) {
  __shared__ __align__(16) unsigned char smem[20480];  // knn: 8K flush bufs; pq: 17.2K w0
  int blk = blockIdx.x;
  int tid = threadIdx.x;

  if (blk < 2048) {
    // ---------------- KNN: 2 queries/wave, register-direct candidates -----
    ull* bufb = (ull*)smem;                       // [4 waves][2 queries][128]
    int lane = tid & 63, w = tid >> 6;
    int b = blk >> 9;                             // 512 blocks per batch
    int n0 = ((blk & 511) << 3) + (w << 1);
    int n1 = n0 + 1;
    const float* xb = xyz + (size_t)b * NPT * 3;
    ull* buf0 = bufb + w * 256;
    ull* buf1 = buf0 + 128;

    float4 q0, q1;
    {
      const float* qp = xb + n0 * 3;
      float ax = qp[0], ay = qp[1], az = qp[2];
      float bx = qp[3], by = qp[4], bz = qp[5];
      q0 = make_float4(ax, ay, az,
          __fadd_rn(__fadd_rn(__fmul_rn(ax, ax), __fmul_rn(ay, ay)), __fmul_rn(az, az)));
      q1 = make_float4(bx, by, bz,
          __fadd_rn(__fadd_rn(__fmul_rn(bx, bx), __fmul_rn(by, by)), __fmul_rn(bz, bz)));
    }
    ull R0 = ~0ull, R1 = ~0ull;
    unsigned th0 = 0xFFFFFFFFu, th1 = 0xFFFFFFFFu;
    int cnt0 = 0, cnt1 = 0;

    // iter-0 preload (lane-resident candidate)
    float cx = xb[3 * lane], cy = xb[3 * lane + 1], cz = xb[3 * lane + 2];
#pragma unroll 1
    for (int g = 0; g < NPT; g += 64) {
      // prefetch next group (wrapped on last iter; values unused)
      int ni = 3 * ((g + 64 + lane) & (NPT - 1));
      float nx = xb[ni], ny = xb[ni + 1], nz = xb[ni + 2];
      float csq = __fadd_rn(__fadd_rn(__fmul_rn(cx, cx), __fmul_rn(cy, cy)),
                            __fmul_rn(cz, cz));
      float4 c = make_float4(cx, cy, cz, csq);
      unsigned idx32 = (unsigned)(g + lane);
      filter_step(q0, c, idx32, th0, cnt0, R0, buf0, lane);
      filter_step(q1, c, idx32, th1, cnt1, R1, buf1, lane);
      cx = nx; cy = ny; cz = nz;
    }
    R0 = final_flush(R0, cnt0, buf0, lane);
    R1 = final_flush(R1, cnt1, buf1, lane);
    if (lane < KNN_K) {
      knnOut[(b * NPT + n0) * KNN_K + lane] = (int)(unsigned)(R0 & 0xFFFFFFFFull);
      knnOut[(b * NPT + n1) * KNN_K + lane] = (int)(unsigned)(R1 & 0xFFFFFFFFull);
    }
    return;
  }

  if (blk < 4096) {
    // ---------------- P/Q precompute: 2 points per wave ------------------
    float* wlds = (float*)smem;                   // [64*67] folded w0
    for (int j = tid; j < 4288; j += 256) {
      int r = j / 67;
      float s = g0[r] * rsqrtf(rv0[r] + EPSV);
      wlds[j] = __fmul_rn(w0[j], s);
    }
    __syncthreads();
    int oc = tid & 63;
    int base = (blk - 2048) * 8 + (tid >> 6);
    float s = g0[oc] * rsqrtf(rv0[oc] + EPSV);
    float b0f = (b0[oc] - rm0[oc]) * s + be0[oc];
    const float* wrow = wlds + oc * 67;           // stride-67 -> 2-way bank (free)
#pragma unroll 1
    for (int pt = 0; pt < 2; ++pt) {
      int i = base + pt * 4;
      float x = xyz[i * 3], y = xyz[i * 3 + 1], z = xyz[i * 3 + 2];
      float qacc = wrow[0] * x;
      qacc = fmaf(wrow[1], y, qacc);
      qacc = fmaf(wrow[2], z, qacc);
      float acc = b0f + qacc;
      const float* prow = points + (size_t)i * 64;
#pragma unroll 4
      for (int c = 0; c < 64; ++c) acc = fmaf(wrow[3 + c], prow[c], acc);
      ws[P_OFF + (size_t)i * 64 + oc] = acc;
      ws[Q_OFF + (size_t)i * 64 + oc] = qacc;
    }
    return;
  }

  // ---------------- weight fold for mlp (W1T/B1/W2T/B2) ------------------
  {
    int i = (blk - 4096) * 256 + tid + 4352;
    if (i < 8448) {
      int j = i - 4352; int oc = j & 63, ic = j >> 6;
      float s = g1[oc] * rsqrtf(rv1[oc] + EPSV);
      ws[i] = w1[oc * 64 + ic] * s;
    } else if (i < 8512) {
      int oc = i - 8448;
      float s = g1[oc] * rsqrtf(rv1[oc] + EPSV);
      ws[i] = (b1[oc] - rm1[oc]) * s + be1[oc];
    } else if (i < 16704) {
      int j = i - 8512; int ic = j >> 7, oc = j & 127;
      float s = g2[oc] * rsqrtf(rv2[oc] + EPSV);
      ws[i] = w2[oc * 64 + ic] * s;               // w2t [ic][oc]
    } else if (i < 16832) {
      int oc = i - 16704;
      float s = g2[oc] * rsqrtf(rv2[oc] + EPSV);
      ws[i] = (b2[oc] - rm2[oc]) * s + be2[oc];
    }
  }
}

// MLP v14 kept byte-identical (best measured; dist-2 pipelined GEMM, 40 KB
// LDS, 4 blocks/CU). Accumulation order bias + ic 0..63 -> bit-identical.
__global__ __launch_bounds__(256, 4) void mlp_kernel(
    const float* __restrict__ wbuf, const int* __restrict__ knn,
    float* __restrict__ out) {
  __shared__ __align__(16) float Ash[64 * 128];   // 32 KB [ic][p]
  __shared__ __align__(16) float Wsh[32 * 64];    // 8 KB chunk [icLocal][oc]
  int tid = threadIdx.x;
  int qblk = blockIdx.x << 3;                     // 8 flat queries per block

  const float4* w1g = (const float4*)(wbuf + W1T_OFF);   // [64][16 f4]
  const float4* w2g = (const float4*)(wbuf + W2T_OFF);   // [64][32 f4]
  float4* wl = (float4*)Wsh;

  // W2 chunk (pass p, ic-half h) entry e in [0,512): row 32h+(e>>4), colf4 16p+(e&15)
#define W2IDX(e, p, h) ((((h) << 5) + ((e) >> 4)) * 32 + ((p) << 4) + ((e) & 15))

  // ---- preload W1a ----
  float4 s0 = w1g[tid];
  float4 s1 = w1g[256 + tid];

  // ---- h0: pair p = tid&127, ic-half = tid>>7 ----
  {
    int p = tid & 127, half = tid >> 7;
    int q = qblk + (p >> 4);
    int k = p & 15;
    int src = knn[q * KNN_K + k];                 // coalesced across 128 threads
    int srow = (q & ~(NPT - 1)) + src;
    const float4* Pp = (const float4*)(wbuf + P_OFF + (size_t)srow * 64 + half * 32);
    const float4* Qp = (const float4*)(wbuf + Q_OFF + (size_t)q * 64 + half * 32);
#pragma unroll
    for (int j = 0; j < 8; ++j) {
      float4 pv = Pp[j];
      float4 qv = Qp[j];
      int ic = half * 32 + j * 4;
      Ash[(ic + 0) * 128 + p] = fmaxf(pv.x - qv.x, 0.0f);
      Ash[(ic + 1) * 128 + p] = fmaxf(pv.y - qv.y, 0.0f);
      Ash[(ic + 2) * 128 + p] = fmaxf(pv.z - qv.z, 0.0f);
      Ash[(ic + 3) * 128 + p] = fmaxf(pv.w - qv.w, 0.0f);
    }
  }
  // write W1a; preload W1b
  wl[tid] = s0; wl[256 + tid] = s1;
  s0 = w1g[512 + tid]; s1 = w1g[768 + tid];
  __syncthreads();                                 // S1: h0 + W1a visible

  int og = tid & 7, pg = tid >> 3;                 // 32 pgrp x 8 ogrp
  const float* Arow = Ash + 4 * pg;
  const float* Wrow = Wsh + 8 * og;
  float acc[4][8];                                 // [pair][oc]

  // distance-2 software-pipelined 32-ic GEMM: loads for ic+2 issue before
  // the FMAs of ic; all register names static after full unroll.
#define LD_A(R0, i)  (*(const float4*)(Arow + ((R0) + (i)) * 128))
#define LD_W0(i)     (*(const float4*)(Wrow + (i) * 64))
#define LD_W1(i)     (*(const float4*)(Wrow + (i) * 64 + 4))
#define GEMM32(R0)                                                        \
  {                                                                       \
    float4 aA = LD_A(R0, 0), wA0 = LD_W0(0), wA1 = LD_W1(0);              \
    float4 aB = LD_A(R0, 1), wB0 = LD_W0(1), wB1 = LD_W1(1);              \
    _Pragma("unroll")                                                     \
    for (int ic = 0; ic < 32; ++ic) {                                     \
      int nx = (ic + 2 <= 31) ? ic + 2 : 31;                              \
      float4 aN = LD_A(R0, nx);                                           \
      float4 wN0 = LD_W0(nx);                                             \
      float4 wN1 = LD_W1(nx);                                             \
      float av[4] = {aA.x, aA.y, aA.z, aA.w};                             \
      float wv[8] = {wA0.x, wA0.y, wA0.z, wA0.w, wA1.x, wA1.y, wA1.z, wA1.w};\
      _Pragma("unroll")                                                   \
      for (int ii = 0; ii < 4; ++ii)                                      \
        _Pragma("unroll")                                                 \
        for (int jj = 0; jj < 8; ++jj) acc[ii][jj] = fmaf(av[ii], wv[jj], acc[ii][jj]); \
      aA = aB; wA0 = wB0; wA1 = wB1;                                      \
      aB = aN; wB0 = wN0; wB1 = wN1;                                      \
    }                                                                     \
  }

  // ---- layer 1 ----
  {
    float4 b0v = *(const float4*)(wbuf + B1_OFF + 8 * og);
    float4 b1v = *(const float4*)(wbuf + B1_OFF + 8 * og + 4);
    float bj[8] = {b0v.x, b0v.y, b0v.z, b0v.w, b1v.x, b1v.y, b1v.z, b1v.w};
#pragma unroll
    for (int i = 0; i < 4; ++i)
#pragma unroll
      for (int j = 0; j < 8; ++j) acc[i][j] = bj[j];
  }
  GEMM32(0)                                        // W1a: ic 0..31
  __syncthreads();                                 // S2: W1a reads done
  wl[tid] = s0; wl[256 + tid] = s1;                // write W1b
  s0 = w2g[W2IDX(tid, 0, 0)]; s1 = w2g[W2IDX(tid + 256, 0, 0)];
  __syncthreads();                                 // S3: W1b visible
  GEMM32(32)                                       // W1b: ic 32..63
  __syncthreads();                                 // S4: all Ash(h0)+W1b reads done

  // h1 -> A[oc][p] (write throughput-limited, once per layer: accepted)
#pragma unroll
  for (int j = 0; j < 8; ++j) {
    int oc = 8 * og + j;
    *(float4*)(Ash + oc * 128 + 4 * pg) =
        make_float4(fmaxf(acc[0][j], 0.0f), fmaxf(acc[1][j], 0.0f),
                    fmaxf(acc[2][j], 0.0f), fmaxf(acc[3][j], 0.0f));
  }
  // stage W2p0a from regs; preload W2p0b
  wl[tid] = s0; wl[256 + tid] = s1;
  s0 = w2g[W2IDX(tid, 0, 1)]; s1 = w2g[W2IDX(tid + 256, 0, 1)];
  __syncthreads();                                 // S5: h1 + W2p0a visible

  int qout = qblk + (pg >> 2);
  float* obase = out + (size_t)qout * 128 + 8 * og;

  // ---- layer 2 pass 0 (oc 0..63) ----
  {
    float4 b0v = *(const float4*)(wbuf + B2_OFF + 8 * og);
    float4 b1v = *(const float4*)(wbuf + B2_OFF + 8 * og + 4);
    float bj[8] = {b0v.x, b0v.y, b0v.z, b0v.w, b1v.x, b1v.y, b1v.z, b1v.w};
#pragma unroll
    for (int i = 0; i < 4; ++i)
#pragma unroll
      for (int j = 0; j < 8; ++j) acc[i][j] = bj[j];
  }
  GEMM32(0)                                        // W2p0a: ic 0..31
  __syncthreads();                                 // S6
  wl[tid] = s0; wl[256 + tid] = s1;                // write W2p0b
  s0 = w2g[W2IDX(tid, 1, 0)]; s1 = w2g[W2IDX(tid + 256, 1, 0)];
  __syncthreads();                                 // S7
  GEMM32(32)                                       // W2p0b: ic 32..63
  {
    float m[8];
#pragma unroll
    for (int j = 0; j < 8; ++j) {
      float v = fmaxf(fmaxf(acc[0][j], acc[1][j]), fmaxf(acc[2][j], acc[3][j]));
      v = fmaxf(v, 0.0f);
      v = fmaxf(v, __shfl_xor(v, 8));              // pg bit 0
      m[j] = fmaxf(v, __shfl_xor(v, 16));          // pg bit 1
    }
    if ((pg & 3) == 0) {
      *(float4*)(obase)     = make_float4(m[0], m[1], m[2], m[3]);
      *(float4*)(obase + 4) = make_float4(m[4], m[5], m[6], m[7]);
    }
  }
  __syncthreads();                                 // S8
  wl[tid] = s0; wl[256 + tid] = s1;                // write W2p1a
  s0 = w2g[W2IDX(tid, 1, 1)]; s1 = w2g[W2IDX(tid + 256, 1, 1)];
  __syncthreads();                                 // S9

  // ---- layer 2 pass 1 (oc 64..127) ----
  {
    float4 b0v = *(const float4*)(wbuf + B2_OFF + 64 + 8 * og);
    float4 b1v = *(const float4*)(wbuf + B2_OFF + 64 + 8 * og + 4);
    float bj[8] = {b0v.x, b0v.y, b0v.z, b0v.w, b1v.x, b1v.y, b1v.z, b1v.w};
#pragma unroll
    for (int i = 0; i < 4; ++i)
#pragma unroll
      for (int j = 0; j < 8; ++j) acc[i][j] = bj[j];
  }
  GEMM32(0)                                        // W2p1a: ic 0..31
  __syncthreads();                                 // S10
  wl[tid] = s0; wl[256 + tid] = s1;                // write W2p1b
  __syncthreads();                                 // S11
  GEMM32(32)                                       // W2p1b: ic 32..63
  {
    float m[8];
#pragma unroll
    for (int j = 0; j < 8; ++j) {
      float v = fmaxf(fmaxf(acc[0][j], acc[1][j]), fmaxf(acc[2][j], acc[3][j]));
      v = fmaxf(v, 0.0f);
      v = fmaxf(v, __shfl_xor(v, 8));
      m[j] = fmaxf(v, __shfl_xor(v, 16));
    }
    if ((pg & 3) == 0) {
      *(float4*)(obase + 64)     = make_float4(m[0], m[1], m[2], m[3]);
      *(float4*)(obase + 64 + 4) = make_float4(m[4], m[5], m[6], m[7]);
    }
  }
#undef GEMM32
#undef LD_A
#undef LD_W0
#undef LD_W1
#undef W2IDX
}

extern "C" void kernel_launch(void* const* d_in, const int* in_sizes, int n_in,
                              void* d_out, int out_size, void* d_ws, size_t ws_size,
                              hipStream_t stream) {
  const float* xyz    = (const float*)d_in[0];
  const float* points = (const float*)d_in[1];
  float* wsF = (float*)d_ws;
  int* idxBuf = (int*)(wsF + IDX_OFF);

  mega_kernel<<<4145, 256, 0, stream>>>(
      xyz, points,
      (const float*)d_in[2],  (const float*)d_in[3],  (const float*)d_in[4],
      (const float*)d_in[5],  (const float*)d_in[6],  (const float*)d_in[7],
      (const float*)d_in[8],  (const float*)d_in[9],  (const float*)d_in[10],
      (const float*)d_in[11], (const float*)d_in[12], (const float*)d_in[13],
      (const float*)d_in[14], (const float*)d_in[15], (const float*)d_in[16],
      (const float*)d_in[17], (const float*)d_in[18], (const float*)d_in[19],
      wsF, idxBuf);
  mlp_kernel<<<2048, 256, 0, stream>>>(wsF, idxBuf, (float*)d_out);
}